// Round 7
// baseline (98.661 us; speedup 1.0000x reference)
//
#include <hip/hip_runtime.h>

#define NN 8192
#define DD 128
#define BI 128            // i-rows per tile
#define BJ 64             // j-cols per tile
#define GX (NN / BJ)      // 128
#define GY (NN / BI)      // 64
#define NBLK (GX * GY)    // 8192

typedef __attribute__((ext_vector_type(8))) short bf16x8;
typedef __attribute__((ext_vector_type(4))) float f32x4;

__device__ __forceinline__ ushort f2bf(float x) {
    unsigned u = __float_as_uint(x);
    unsigned r = u + 0x7FFFu + ((u >> 16) & 1u);
    return (ushort)(r >> 16);
}

__device__ __forceinline__ void async16(void* lds, const void* g) {
    __builtin_amdgcn_global_load_lds(
        (const __attribute__((address_space(1))) unsigned*)g,
        (__attribute__((address_space(3))) unsigned*)lds, 16, 0, 0);
}

// Kernel 0: sq[i] = ||f_i||^2; Fbf = bf16(F) (fast path).
__global__ void prep_kernel(const float* __restrict__ F, ushort* __restrict__ Fbf,
                            float* __restrict__ sq, int doFbf) {
    int gtid = blockIdx.x * blockDim.x + threadIdx.x;
    int row  = gtid >> 6;
    int lane = threadIdx.x & 63;
    const float2 v = *(const float2*)(F + (size_t)row * DD + lane * 2);
    if (doFbf)
        ((ushort2*)(Fbf + (size_t)row * DD))[lane] = make_ushort2(f2bf(v.x), f2bf(v.y));
    float s = v.x * v.x + v.y * v.y;
    #pragma unroll
    for (int off = 32; off > 0; off >>= 1) s += __shfl_down(s, off);
    if (lane == 0) sq[row] = s;
}

// Fast path: 128x64 S-tile per block. P = F_j . F_i^T via MFMA (swapped
// operands: acc regs = 4 consecutive j-columns of S). F_i staged in LDS
// (exactly 32 KB); F_j fragments direct from L2-resident Fbf.
// S loads issued AFTER the barrier so they overlap the MFMA phase
// (__syncthreads drains vmcnt(0) — pre-barrier prefetch is useless).
__global__ __launch_bounds__(256, 5) void tile_kernel(
        const ushort* __restrict__ Fbf, const float* __restrict__ S,
        const float* __restrict__ sq, float* __restrict__ partials) {
    __shared__ ushort lI[BI * DD];    // F_i panel, XOR-swizzled rows (32 KB)

    const int gi  = blockIdx.y * BI;
    const int gj  = blockIdx.x * BJ;
    const int tid = threadIdx.x;
    const int w = tid >> 6, l = tid & 63;
    const int fr = l & 15, g = l >> 4;
    const int jw = w * 16;                 // wave's 16-col j-window

    // ---- (1) stage F_i: linear LDS dest, inverse-swizzled global source ----
    #pragma unroll
    for (int it = 0; it < 8; ++it) {
        const int c   = it * 4 + w;                 // 1 KB chunk = 4 rows
        const int row = c * 4 + (l >> 4);
        const int src = ((l & 15) * 16) ^ ((row & 7) << 4);
        async16((char*)lI + c * 1024, (const char*)(Fbf + (size_t)(gi + row) * DD) + src);
    }

    // ---- (2) small L2 loads (af/si/sj) — all drained at the barrier anyway ----
    bf16x8 af[4];
    #pragma unroll
    for (int kk = 0; kk < 4; ++kk)
        af[kk] = *(const bf16x8*)(Fbf + (size_t)(gj + jw + fr) * DD + kk * 32 + g * 8);
    float si[8];
    #pragma unroll
    for (int ct = 0; ct < 8; ++ct) si[ct] = sq[gi + ct * 16 + fr];
    const float4 sjv = *(const float4*)(sq + gj + jw + g * 4);

    // ---- (3) barrier: waits LDS staging (+ the small loads) ----
    __syncthreads();

    // ---- (4) NOW issue the HBM S loads; they fly under the MFMA phase ----
    f32x4 sv[8];
    const float* sb = S + (size_t)(gi + fr) * NN + gj + jw + g * 4;
    #pragma unroll
    for (int ct = 0; ct < 8; ++ct)
        sv[ct] = *(const f32x4*)(sb + (size_t)ct * 16 * NN);
    __builtin_amdgcn_sched_barrier(0);   // pin: S issued before any MFMA/ds_read

    // ---- (5) MFMA: acc[ct] = P[j = jw+g*4+r][i = ct*16+fr] (LDS, lgkmcnt) ----
    f32x4 acc[8];
    #pragma unroll
    for (int ct = 0; ct < 8; ++ct) acc[ct] = (f32x4){0.f, 0.f, 0.f, 0.f};
    #pragma unroll
    for (int ct = 0; ct < 8; ++ct) {
        const int row = ct * 16 + fr;
        const int sw  = (row & 7) << 4;
        #pragma unroll
        for (int kk = 0; kk < 4; ++kk) {
            const bf16x8 bfr = *(const bf16x8*)((const char*)lI + row * 256 +
                                                ((kk * 64 + g * 16) ^ sw));
            acc[ct] = __builtin_amdgcn_mfma_f32_16x16x32_bf16(af[kk], bfr, acc[ct], 0, 0, 0);
        }
    }

    // ---- (6) consume S: part += S*(sq_i + sq_j - 2*P) ----
    float part0 = 0.f, part1 = 0.f;
    #pragma unroll
    for (int ct = 0; ct < 8; ++ct) {
        const f32x4 s4 = sv[ct];
        const float sic = si[ct];
        part0 += s4.x * ((sic + sjv.x) - 2.f * acc[ct][0]);
        part1 += s4.y * ((sic + sjv.y) - 2.f * acc[ct][1]);
        part0 += s4.z * ((sic + sjv.z) - 2.f * acc[ct][2]);
        part1 += s4.w * ((sic + sjv.w) - 2.f * acc[ct][3]);
    }
    float part = part0 + part1;

    // ---- (7) wave reduction; per-wave partial store (no LDS, no barrier) ----
    #pragma unroll
    for (int off = 32; off > 0; off >>= 1) part += __shfl_down(part, off);
    if (l == 0)
        partials[(size_t)(blockIdx.y * gridDim.x + blockIdx.x) * 4 + w] = part;
}

// ---------------- fallback path (tiny workspace): R2-style ----------------
__global__ __launch_bounds__(256, 2) void tile_fb_kernel(
        const float* __restrict__ F, const float* __restrict__ S,
        const float* __restrict__ sq, float* __restrict__ partials) {
    __shared__ ushort lI[BI * DD];
    __shared__ ushort lJ[BI * DD];
    __shared__ float  sqi[BI];
    __shared__ float  sqj[BI];
    __shared__ float  red[4];

    const int gi = blockIdx.y * BI, gj = blockIdx.x * BI;
    const int tid = threadIdx.x;
    const int w = tid >> 6, l = tid & 63;

    const int r0 = tid >> 5;
    const int c4 = (tid & 31) * 4;
    #pragma unroll
    for (int it = 0; it < 16; ++it) {
        const int row = it * 8 + r0;
        const float4 va = *(const float4*)(F + (size_t)(gi + row) * DD + c4);
        const float4 vb = *(const float4*)(F + (size_t)(gj + row) * DD + c4);
        int byte = row * 256 + c4 * 2;
        byte ^= (row & 7) << 4;
        *(ushort4*)((char*)lI + byte) =
            make_ushort4(f2bf(va.x), f2bf(va.y), f2bf(va.z), f2bf(va.w));
        *(ushort4*)((char*)lJ + byte) =
            make_ushort4(f2bf(vb.x), f2bf(vb.y), f2bf(vb.z), f2bf(vb.w));
    }
    if (tid < 128) sqi[tid] = sq[gi + tid];
    else           sqj[tid - 128] = sq[gj + tid - 128];
    __syncthreads();

    const int fr = l & 15;
    const int g  = l >> 4;
    const int jw = w * 32;

    float4 sv0[8], sv1[8];
    #pragma unroll
    for (int ct = 0; ct < 8; ++ct) {
        const float* srow = S + (size_t)(gi + ct * 16 + fr) * NN + gj + jw + g * 4;
        sv0[ct] = *(const float4*)(srow);
        sv1[ct] = *(const float4*)(srow + 16);
    }

    bf16x8 afrag[2][4];
    #pragma unroll
    for (int kk = 0; kk < 4; ++kk) {
        int row = jw + fr;
        int byte = row * 256 + kk * 64 + g * 16; byte ^= (row & 7) << 4;
        afrag[0][kk] = *(const bf16x8*)((const char*)lJ + byte);
        row = jw + 16 + fr;
        byte = row * 256 + kk * 64 + g * 16; byte ^= (row & 7) << 4;
        afrag[1][kk] = *(const bf16x8*)((const char*)lJ + byte);
    }

    f32x4 acc[2][8];
    #pragma unroll
    for (int ct = 0; ct < 8; ++ct) {
        acc[0][ct] = (f32x4){0.f, 0.f, 0.f, 0.f};
        acc[1][ct] = (f32x4){0.f, 0.f, 0.f, 0.f};
    }
    #pragma unroll
    for (int ct = 0; ct < 8; ++ct) {
        #pragma unroll
        for (int kk = 0; kk < 4; ++kk) {
            const int row = ct * 16 + fr;
            int byte = row * 256 + kk * 64 + g * 16; byte ^= (row & 7) << 4;
            const bf16x8 bfrag = *(const bf16x8*)((const char*)lI + byte);
            acc[0][ct] = __builtin_amdgcn_mfma_f32_16x16x32_bf16(afrag[0][kk], bfrag, acc[0][ct], 0, 0, 0);
            acc[1][ct] = __builtin_amdgcn_mfma_f32_16x16x32_bf16(afrag[1][kk], bfrag, acc[1][ct], 0, 0, 0);
        }
    }

    const float4 sj0 = *(const float4*)(sqj + jw + g * 4);
    const float4 sj1 = *(const float4*)(sqj + jw + 16 + g * 4);
    float part = 0.f;
    #pragma unroll
    for (int ct = 0; ct < 8; ++ct) {
        const float sic = sqi[ct * 16 + fr];
        const float4 s0 = sv0[ct], s1 = sv1[ct];
        part += s0.x * (sic + sj0.x - 2.f * acc[0][ct][0]);
        part += s0.y * (sic + sj0.y - 2.f * acc[0][ct][1]);
        part += s0.z * (sic + sj0.z - 2.f * acc[0][ct][2]);
        part += s0.w * (sic + sj0.w - 2.f * acc[0][ct][3]);
        part += s1.x * (sic + sj1.x - 2.f * acc[1][ct][0]);
        part += s1.y * (sic + sj1.y - 2.f * acc[1][ct][1]);
        part += s1.z * (sic + sj1.z - 2.f * acc[1][ct][2]);
        part += s1.w * (sic + sj1.w - 2.f * acc[1][ct][3]);
    }

    #pragma unroll
    for (int off = 32; off > 0; off >>= 1) part += __shfl_down(part, off);
    if (l == 0) red[w] = part;
    __syncthreads();
    if (tid == 0)
        partials[blockIdx.y * gridDim.x + blockIdx.x] = (red[0] + red[1]) + (red[2] + red[3]);
}

__global__ void reduce_kernel(const float* __restrict__ partials, float* __restrict__ out, int n) {
    __shared__ float sm[256];
    const int t = threadIdx.x;
    float s = 0.f;
    for (int i = t; i < n; i += 256) s += partials[i];
    sm[t] = s;
    __syncthreads();
    for (int off = 128; off > 0; off >>= 1) {
        if (t < off) sm[t] += sm[t + off];
        __syncthreads();
    }
    if (t == 0) out[0] = sm[0];
}

extern "C" void kernel_launch(void* const* d_in, const int* in_sizes, int n_in,
                              void* d_out, int out_size, void* d_ws, size_t ws_size,
                              hipStream_t stream) {
    const float* F = (const float*)d_in[0];
    const float* S = (const float*)d_in[1];
    float* sq        = (float*)d_ws;                        // 32 KB
    float* partials  = sq + NN;                             // 128 KB (32768 floats)
    ushort* Fbf      = (ushort*)((char*)d_ws + 192 * 1024); // 2 MB
    float* out       = (float*)d_out;

    const size_t need = 192 * 1024 + (size_t)NN * DD * 2 + 256;
    const int fast = (ws_size >= need) ? 1 : 0;

    prep_kernel<<<NN / 4, 256, 0, stream>>>(F, Fbf, sq, fast);
    if (fast) {
        tile_kernel<<<dim3(GX, GY), 256, 0, stream>>>(Fbf, S, sq, partials);
        reduce_kernel<<<1, 256, 0, stream>>>(partials, out, NBLK * 4);
    } else {
        tile_fb_kernel<<<dim3(GY, GY), 256, 0, stream>>>(F, S, sq, partials);
        reduce_kernel<<<1, 256, 0, stream>>>(partials, out, GY * GY);
    }
}

// Round 8
// 76.716 us; speedup vs baseline: 1.2861x; 1.2861x over previous
//
#include <hip/hip_runtime.h>

#define NN 8192
#define DD 128
#define BI 128            // i-rows per tile
#define BJ 64             // j-cols per tile
#define GX (NN / BJ)      // 128
#define GY (NN / BI)      // 64
#define NBLK (GX * GY)    // 8192

typedef __attribute__((ext_vector_type(8))) short bf16x8;
typedef __attribute__((ext_vector_type(4))) float f32x4;

__device__ __forceinline__ ushort f2bf(float x) {
    unsigned u = __float_as_uint(x);
    unsigned r = u + 0x7FFFu + ((u >> 16) & 1u);
    return (ushort)(r >> 16);
}

__device__ __forceinline__ void async16(void* lds, const void* g) {
    __builtin_amdgcn_global_load_lds(
        (const __attribute__((address_space(1))) unsigned*)g,
        (__attribute__((address_space(3))) unsigned*)lds, 16, 0, 0);
}

// Kernel 0: sq[i] = ||f_i||^2; Fbf = bf16(F) (fast path).
__global__ void prep_kernel(const float* __restrict__ F, ushort* __restrict__ Fbf,
                            float* __restrict__ sq, int doFbf) {
    int gtid = blockIdx.x * blockDim.x + threadIdx.x;
    int row  = gtid >> 6;
    int lane = threadIdx.x & 63;
    const float2 v = *(const float2*)(F + (size_t)row * DD + lane * 2);
    if (doFbf)
        ((ushort2*)(Fbf + (size_t)row * DD))[lane] = make_ushort2(f2bf(v.x), f2bf(v.y));
    float s = v.x * v.x + v.y * v.y;
    #pragma unroll
    for (int off = 32; off > 0; off >>= 1) s += __shfl_down(s, off);
    if (lane == 0) sq[row] = s;
}

// Fast path: 128x64 S-tile per block. P = F_j . F_i^T via MFMA (swapped
// operands: acc regs = 4 consecutive j-columns of S). F_i staged in LDS
// (32 KB, 4 blocks/CU); F_j fragments direct from L2-resident Fbf.
// S loads issued AFTER the barrier so they overlap the MFMA phase.
// launch_bounds(256,4): VGPR cap 128 — fits sv+acc+af live set, NO spill
// (bound 5 capped at ~96 and spilled sv -> R7's 98us regression).
__global__ __launch_bounds__(256, 4) void tile_kernel(
        const ushort* __restrict__ Fbf, const float* __restrict__ S,
        const float* __restrict__ sq, float* __restrict__ partials) {
    __shared__ ushort lI[BI * DD];    // F_i panel, XOR-swizzled rows (32 KB)
    __shared__ float  red[4];

    const int gi  = blockIdx.y * BI;
    const int gj  = blockIdx.x * BJ;
    const int tid = threadIdx.x;
    const int w = tid >> 6, l = tid & 63;
    const int fr = l & 15, g = l >> 4;
    const int jw = w * 16;                 // wave's 16-col j-window

    // ---- (1) stage F_i: linear LDS dest, inverse-swizzled global source ----
    #pragma unroll
    for (int it = 0; it < 8; ++it) {
        const int c   = it * 4 + w;                 // 1 KB chunk = 4 rows
        const int row = c * 4 + (l >> 4);
        const int src = ((l & 15) * 16) ^ ((row & 7) << 4);
        async16((char*)lI + c * 1024, (const char*)(Fbf + (size_t)(gi + row) * DD) + src);
    }

    // ---- (2) small L2 loads (af/si/sj) — drained at the barrier ----
    bf16x8 af[4];
    #pragma unroll
    for (int kk = 0; kk < 4; ++kk)
        af[kk] = *(const bf16x8*)(Fbf + (size_t)(gj + jw + fr) * DD + kk * 32 + g * 8);
    float si[8];
    #pragma unroll
    for (int ct = 0; ct < 8; ++ct) si[ct] = sq[gi + ct * 16 + fr];
    const float4 sjv = *(const float4*)(sq + gj + jw + g * 4);

    // ---- (3) barrier: waits LDS staging ----
    __syncthreads();

    // ---- (4) issue HBM S loads; they fly under the MFMA phase ----
    f32x4 sv[8];
    const float* sb = S + (size_t)(gi + fr) * NN + gj + jw + g * 4;
    #pragma unroll
    for (int ct = 0; ct < 8; ++ct)
        sv[ct] = *(const f32x4*)(sb + (size_t)ct * 16 * NN);
    __builtin_amdgcn_sched_barrier(0);   // pin: S issued before MFMA/ds_read

    // ---- (5) MFMA: acc[ct] = P[j = jw+g*4+r][i = ct*16+fr] (LDS, lgkmcnt) ----
    f32x4 acc[8];
    #pragma unroll
    for (int ct = 0; ct < 8; ++ct) acc[ct] = (f32x4){0.f, 0.f, 0.f, 0.f};
    #pragma unroll
    for (int ct = 0; ct < 8; ++ct) {
        const int row = ct * 16 + fr;
        const int sw  = (row & 7) << 4;
        #pragma unroll
        for (int kk = 0; kk < 4; ++kk) {
            const bf16x8 bfr = *(const bf16x8*)((const char*)lI + row * 256 +
                                                ((kk * 64 + g * 16) ^ sw));
            acc[ct] = __builtin_amdgcn_mfma_f32_16x16x32_bf16(af[kk], bfr, acc[ct], 0, 0, 0);
        }
    }

    // ---- (6) consume S: part += S*(sq_i + sq_j - 2*P) ----
    float part0 = 0.f, part1 = 0.f;
    #pragma unroll
    for (int ct = 0; ct < 8; ++ct) {
        const f32x4 s4 = sv[ct];
        const float sic = si[ct];
        part0 += s4.x * ((sic + sjv.x) - 2.f * acc[ct][0]);
        part1 += s4.y * ((sic + sjv.y) - 2.f * acc[ct][1]);
        part0 += s4.z * ((sic + sjv.z) - 2.f * acc[ct][2]);
        part1 += s4.w * ((sic + sjv.w) - 2.f * acc[ct][3]);
    }
    float part = part0 + part1;

    // ---- (7) deterministic block reduction; one partial per block ----
    #pragma unroll
    for (int off = 32; off > 0; off >>= 1) part += __shfl_down(part, off);
    if (l == 0) red[w] = part;
    __syncthreads();
    if (tid == 0)
        partials[blockIdx.y * gridDim.x + blockIdx.x] =
            (red[0] + red[1]) + (red[2] + red[3]);
}

// ---------------- fallback path (tiny workspace): R2-style ----------------
__global__ __launch_bounds__(256, 2) void tile_fb_kernel(
        const float* __restrict__ F, const float* __restrict__ S,
        const float* __restrict__ sq, float* __restrict__ partials) {
    __shared__ ushort lI[BI * DD];
    __shared__ ushort lJ[BI * DD];
    __shared__ float  sqi[BI];
    __shared__ float  sqj[BI];
    __shared__ float  red[4];

    const int gi = blockIdx.y * BI, gj = blockIdx.x * BI;
    const int tid = threadIdx.x;
    const int w = tid >> 6, l = tid & 63;

    const int r0 = tid >> 5;
    const int c4 = (tid & 31) * 4;
    #pragma unroll
    for (int it = 0; it < 16; ++it) {
        const int row = it * 8 + r0;
        const float4 va = *(const float4*)(F + (size_t)(gi + row) * DD + c4);
        const float4 vb = *(const float4*)(F + (size_t)(gj + row) * DD + c4);
        int byte = row * 256 + c4 * 2;
        byte ^= (row & 7) << 4;
        *(ushort4*)((char*)lI + byte) =
            make_ushort4(f2bf(va.x), f2bf(va.y), f2bf(va.z), f2bf(va.w));
        *(ushort4*)((char*)lJ + byte) =
            make_ushort4(f2bf(vb.x), f2bf(vb.y), f2bf(vb.z), f2bf(vb.w));
    }
    if (tid < 128) sqi[tid] = sq[gi + tid];
    else           sqj[tid - 128] = sq[gj + tid - 128];
    __syncthreads();

    const int fr = l & 15;
    const int g  = l >> 4;
    const int jw = w * 32;

    float4 sv0[8], sv1[8];
    #pragma unroll
    for (int ct = 0; ct < 8; ++ct) {
        const float* srow = S + (size_t)(gi + ct * 16 + fr) * NN + gj + jw + g * 4;
        sv0[ct] = *(const float4*)(srow);
        sv1[ct] = *(const float4*)(srow + 16);
    }

    bf16x8 afrag[2][4];
    #pragma unroll
    for (int kk = 0; kk < 4; ++kk) {
        int row = jw + fr;
        int byte = row * 256 + kk * 64 + g * 16; byte ^= (row & 7) << 4;
        afrag[0][kk] = *(const bf16x8*)((const char*)lJ + byte);
        row = jw + 16 + fr;
        byte = row * 256 + kk * 64 + g * 16; byte ^= (row & 7) << 4;
        afrag[1][kk] = *(const bf16x8*)((const char*)lJ + byte);
    }

    f32x4 acc[2][8];
    #pragma unroll
    for (int ct = 0; ct < 8; ++ct) {
        acc[0][ct] = (f32x4){0.f, 0.f, 0.f, 0.f};
        acc[1][ct] = (f32x4){0.f, 0.f, 0.f, 0.f};
    }
    #pragma unroll
    for (int ct = 0; ct < 8; ++ct) {
        #pragma unroll
        for (int kk = 0; kk < 4; ++kk) {
            const int row = ct * 16 + fr;
            int byte = row * 256 + kk * 64 + g * 16; byte ^= (row & 7) << 4;
            const bf16x8 bfrag = *(const bf16x8*)((const char*)lI + byte);
            acc[0][ct] = __builtin_amdgcn_mfma_f32_16x16x32_bf16(afrag[0][kk], bfrag, acc[0][ct], 0, 0, 0);
            acc[1][ct] = __builtin_amdgcn_mfma_f32_16x16x32_bf16(afrag[1][kk], bfrag, acc[1][ct], 0, 0, 0);
        }
    }

    const float4 sj0 = *(const float4*)(sqj + jw + g * 4);
    const float4 sj1 = *(const float4*)(sqj + jw + 16 + g * 4);
    float part = 0.f;
    #pragma unroll
    for (int ct = 0; ct < 8; ++ct) {
        const float sic = sqi[ct * 16 + fr];
        const float4 s0 = sv0[ct], s1 = sv1[ct];
        part += s0.x * (sic + sj0.x - 2.f * acc[0][ct][0]);
        part += s0.y * (sic + sj0.y - 2.f * acc[0][ct][1]);
        part += s0.z * (sic + sj0.z - 2.f * acc[0][ct][2]);
        part += s0.w * (sic + sj0.w - 2.f * acc[0][ct][3]);
        part += s1.x * (sic + sj1.x - 2.f * acc[1][ct][0]);
        part += s1.y * (sic + sj1.y - 2.f * acc[1][ct][1]);
        part += s1.z * (sic + sj1.z - 2.f * acc[1][ct][2]);
        part += s1.w * (sic + sj1.w - 2.f * acc[1][ct][3]);
    }

    #pragma unroll
    for (int off = 32; off > 0; off >>= 1) part += __shfl_down(part, off);
    if (l == 0) red[w] = part;
    __syncthreads();
    if (tid == 0)
        partials[blockIdx.y * gridDim.x + blockIdx.x] = (red[0] + red[1]) + (red[2] + red[3]);
}

__global__ void reduce_kernel(const float* __restrict__ partials, float* __restrict__ out, int n) {
    __shared__ float sm[256];
    const int t = threadIdx.x;
    float s = 0.f;
    for (int i = t; i < n; i += 256) s += partials[i];
    sm[t] = s;
    __syncthreads();
    for (int off = 128; off > 0; off >>= 1) {
        if (t < off) sm[t] += sm[t + off];
        __syncthreads();
    }
    if (t == 0) out[0] = sm[0];
}

extern "C" void kernel_launch(void* const* d_in, const int* in_sizes, int n_in,
                              void* d_out, int out_size, void* d_ws, size_t ws_size,
                              hipStream_t stream) {
    const float* F = (const float*)d_in[0];
    const float* S = (const float*)d_in[1];
    float* sq        = (float*)d_ws;                        // 32 KB
    float* partials  = sq + NN;                             // 32 KB (8192 floats)
    ushort* Fbf      = (ushort*)((char*)d_ws + 128 * 1024); // 2 MB
    float* out       = (float*)d_out;

    const size_t need = 128 * 1024 + (size_t)NN * DD * 2 + 256;
    const int fast = (ws_size >= need) ? 1 : 0;

    prep_kernel<<<NN / 4, 256, 0, stream>>>(F, Fbf, sq, fast);
    if (fast) {
        tile_kernel<<<dim3(GX, GY), 256, 0, stream>>>(Fbf, S, sq, partials);
        reduce_kernel<<<1, 256, 0, stream>>>(partials, out, NBLK);
    } else {
        tile_fb_kernel<<<dim3(GY, GY), 256, 0, stream>>>(F, S, sq, partials);
        reduce_kernel<<<1, 256, 0, stream>>>(partials, out, GY * GY);
    }
}

// Round 9
// 74.347 us; speedup vs baseline: 1.3270x; 1.0319x over previous
//
#include <hip/hip_runtime.h>

#define NN 8192
#define DD 128
#define BM 128
#define NTILE (NN / BM)   // 64

typedef __attribute__((ext_vector_type(8))) short bf16x8;
typedef __attribute__((ext_vector_type(4))) float f32x4;

__device__ __forceinline__ ushort f2bf(float x) {
    unsigned u = __float_as_uint(x);
    unsigned r = u + 0x7FFFu + ((u >> 16) & 1u);
    return (ushort)(r >> 16);
}

__device__ __forceinline__ void async16(void* lds, const void* g) {
    __builtin_amdgcn_global_load_lds(
        (const __attribute__((address_space(1))) unsigned*)g,
        (__attribute__((address_space(3))) unsigned*)lds, 16, 0, 0);
}
__device__ __forceinline__ void async4(void* lds, const void* g) {
    __builtin_amdgcn_global_load_lds(
        (const __attribute__((address_space(1))) unsigned*)g,
        (__attribute__((address_space(3))) unsigned*)lds, 4, 0, 0);
}

// Kernel 0: sq[i] = ||f_i||^2 (always); Fbf = bf16(F) (if doFbf).
__global__ void prep_kernel(const float* __restrict__ F, ushort* __restrict__ Fbf,
                            float* __restrict__ sq, int doFbf) {
    int gtid = blockIdx.x * blockDim.x + threadIdx.x;
    int row  = gtid >> 6;
    int lane = threadIdx.x & 63;
    const float2 v = *(const float2*)(F + (size_t)row * DD + lane * 2);
    if (doFbf)
        ((ushort2*)(Fbf + (size_t)row * DD))[lane] = make_ushort2(f2bf(v.x), f2bf(v.y));
    float s = v.x * v.x + v.y * v.y;
    #pragma unroll
    for (int off = 32; off > 0; off >>= 1) s += __shfl_down(s, off);
    if (lane == 0) sq[row] = s;
}

// Kernel 1: per 128x128 S-tile, partial = sum S_ij*(sq_i + sq_j - 2*f_i.f_j)
// Operand-swapped MFMA: D = F_j . F_i^T so acc regs = 4 consecutive j-columns.
// EXACT R2 structure (measured 69.1us) + nontemporal S loads (keep Fbf in L2).
template <int FAST>
__global__ __launch_bounds__(256, 2) void tile_kernel(
        const ushort* __restrict__ Fbf, const float* __restrict__ F,
        const float* __restrict__ S, const float* __restrict__ sq,
        float* __restrict__ partials) {
    __shared__ ushort lI[BM * DD];   // F_i panel (B-operand), swizzled
    __shared__ ushort lJ[BM * DD];   // F_j panel (A-operand), swizzled
    __shared__ float  sqi[BM];
    __shared__ float  sqj[BM];
    __shared__ float  red[4];

    const int bi = blockIdx.y, bj = blockIdx.x;
    const int gi = bi * BM, gj = bj * BM;
    const int tid = threadIdx.x;
    const int w = tid >> 6, l = tid & 63;

    if (FAST) {
        // ---- stage via global_load_lds: linear LDS dest, pre-swizzled global src ----
        #pragma unroll
        for (int it = 0; it < 8; ++it) {
            const int chunk = it * 4 + w;            // 1 KB chunks, 32 per panel
            const int row = chunk * 4 + (l >> 4);    // LDS row this lane lands in
            const int inb = (l & 15) * 16;           // in-row byte
            const int src = inb ^ ((row & 7) << 4);  // inverse swizzle on source
            async16((char*)lI + chunk * 1024, (const char*)(Fbf + (size_t)(gi + row) * DD) + src);
            async16((char*)lJ + chunk * 1024, (const char*)(Fbf + (size_t)(gj + row) * DD) + src);
        }
        {
            float* dstb = (w < 2 ? sqi : sqj) + (w & 1) * 64;
            const float* srcb = sq + (w < 2 ? gi : gj) + (w & 1) * 64 + l;
            async4(dstb, srcb);
        }
    } else {
        // ---- fallback: convert fp32->bf16 in-kernel ----
        const int r0 = tid >> 5;
        const int c4 = (tid & 31) * 4;
        #pragma unroll
        for (int it = 0; it < 16; ++it) {
            const int row = it * 8 + r0;
            const float4 va = *(const float4*)(F + (size_t)(gi + row) * DD + c4);
            const float4 vb = *(const float4*)(F + (size_t)(gj + row) * DD + c4);
            int byte = row * 256 + c4 * 2;
            byte ^= (row & 7) << 4;
            *(ushort4*)((char*)lI + byte) =
                make_ushort4(f2bf(va.x), f2bf(va.y), f2bf(va.z), f2bf(va.w));
            *(ushort4*)((char*)lJ + byte) =
                make_ushort4(f2bf(vb.x), f2bf(vb.y), f2bf(vb.z), f2bf(vb.w));
        }
        if (tid < 128) sqi[tid] = sq[gi + tid];
        else           sqj[tid - 128] = sq[gj + tid - 128];
    }
    __syncthreads();

    const int fr = l & 15;
    const int g  = l >> 4;
    const int jw = w * 32;            // wave's 32-col j window in tile

    // ---- S loads first (after barrier): nontemporal so S never evicts Fbf
    //      from L2; they fly under the LDS-fragment reads + MFMAs below ----
    f32x4 sv0[8], sv1[8];
    #pragma unroll
    for (int ct = 0; ct < 8; ++ct) {
        const float* srow = S + (size_t)(gi + ct * 16 + fr) * NN + gj + jw + g * 4;
        sv0[ct] = __builtin_nontemporal_load((const f32x4*)(srow));
        sv1[ct] = __builtin_nontemporal_load((const f32x4*)(srow + 16));
    }
    __builtin_amdgcn_sched_barrier(0);   // pin: S issued before MFMA/ds_read

    // ---- A fragments from F_j panel ----
    bf16x8 afrag[2][4];
    #pragma unroll
    for (int kk = 0; kk < 4; ++kk) {
        {
            const int row = jw + fr;
            int byte = row * 256 + kk * 64 + g * 16;
            byte ^= (row & 7) << 4;
            afrag[0][kk] = *(const bf16x8*)((const char*)lJ + byte);
        }
        {
            const int row = jw + 16 + fr;
            int byte = row * 256 + kk * 64 + g * 16;
            byte ^= (row & 7) << 4;
            afrag[1][kk] = *(const bf16x8*)((const char*)lJ + byte);
        }
    }

    f32x4 acc[2][8];
    #pragma unroll
    for (int ct = 0; ct < 8; ++ct) {
        acc[0][ct] = (f32x4){0.f, 0.f, 0.f, 0.f};
        acc[1][ct] = (f32x4){0.f, 0.f, 0.f, 0.f};
    }

    // ---- MFMA: D = F_j . F_i^T  (S loads in flight underneath) ----
    #pragma unroll
    for (int ct = 0; ct < 8; ++ct) {
        #pragma unroll
        for (int kk = 0; kk < 4; ++kk) {
            const int row = ct * 16 + fr;
            int byte = row * 256 + kk * 64 + g * 16;
            byte ^= (row & 7) << 4;
            const bf16x8 bfrag = *(const bf16x8*)((const char*)lI + byte);
            acc[0][ct] = __builtin_amdgcn_mfma_f32_16x16x32_bf16(
                afrag[0][kk], bfrag, acc[0][ct], 0, 0, 0);
            acc[1][ct] = __builtin_amdgcn_mfma_f32_16x16x32_bf16(
                afrag[1][kk], bfrag, acc[1][ct], 0, 0, 0);
        }
    }

    // ---- consume: part += S * (sq_i + sq_j - 2*P) ----
    const float4 sj0 = *(const float4*)(sqj + jw + g * 4);
    const float4 sj1 = *(const float4*)(sqj + jw + 16 + g * 4);
    float part = 0.f;
    #pragma unroll
    for (int ct = 0; ct < 8; ++ct) {
        const float si = sqi[ct * 16 + fr];
        const f32x4 s0 = sv0[ct], s1 = sv1[ct];
        part += s0.x * (si + sj0.x - 2.f * acc[0][ct][0]);
        part += s0.y * (si + sj0.y - 2.f * acc[0][ct][1]);
        part += s0.z * (si + sj0.z - 2.f * acc[0][ct][2]);
        part += s0.w * (si + sj0.w - 2.f * acc[0][ct][3]);
        part += s1.x * (si + sj1.x - 2.f * acc[1][ct][0]);
        part += s1.y * (si + sj1.y - 2.f * acc[1][ct][1]);
        part += s1.z * (si + sj1.z - 2.f * acc[1][ct][2]);
        part += s1.w * (si + sj1.w - 2.f * acc[1][ct][3]);
    }

    // ---- deterministic block reduction ----
    #pragma unroll
    for (int off = 32; off > 0; off >>= 1) part += __shfl_down(part, off);
    if (l == 0) red[w] = part;
    __syncthreads();
    if (tid == 0)
        partials[blockIdx.y * gridDim.x + blockIdx.x] = (red[0] + red[1]) + (red[2] + red[3]);
}

// Kernel 2: fixed-order final reduction
__global__ void reduce_kernel(const float* __restrict__ partials, float* __restrict__ out) {
    __shared__ float sm[256];
    const int t = threadIdx.x;
    float s = 0.f;
    for (int i = t; i < NTILE * NTILE; i += 256) s += partials[i];
    sm[t] = s;
    __syncthreads();
    for (int off = 128; off > 0; off >>= 1) {
        if (t < off) sm[t] += sm[t + off];
        __syncthreads();
    }
    if (t == 0) out[0] = sm[0];
}

extern "C" void kernel_launch(void* const* d_in, const int* in_sizes, int n_in,
                              void* d_out, int out_size, void* d_ws, size_t ws_size,
                              hipStream_t stream) {
    const float* F = (const float*)d_in[0];
    const float* S = (const float*)d_in[1];
    float* sq       = (float*)d_ws;                       // 32 KB
    float* partials = sq + NN;                            // 16 KB
    ushort* Fbf     = (ushort*)((char*)d_ws + 48 * 1024); // 2 MB
    float* out      = (float*)d_out;

    const size_t need = 48 * 1024 + (size_t)NN * DD * 2 + 256;
    const int fast = (ws_size >= need) ? 1 : 0;

    prep_kernel<<<NN / 4, 256, 0, stream>>>(F, Fbf, sq, fast);
    dim3 grid(NTILE, NTILE);
    if (fast)
        tile_kernel<1><<<grid, 256, 0, stream>>>(Fbf, F, S, sq, partials);
    else
        tile_kernel<0><<<grid, 256, 0, stream>>>(Fbf, F, S, sq, partials);
    reduce_kernel<<<1, 256, 0, stream>>>(partials, out);
}

// Round 10
// 64.094 us; speedup vs baseline: 1.5393x; 1.1600x over previous
//
#include <hip/hip_runtime.h>

#define NN 8192
#define DD 128
#define BM 128
#define NTILE (NN / BM)   // 64

typedef __attribute__((ext_vector_type(8))) short bf16x8;
typedef __attribute__((ext_vector_type(4))) float f32x4;

__device__ __forceinline__ ushort f2bf(float x) {
    unsigned u = __float_as_uint(x);
    unsigned r = u + 0x7FFFu + ((u >> 16) & 1u);
    return (ushort)(r >> 16);
}

__device__ __forceinline__ void async16(void* lds, const void* g) {
    __builtin_amdgcn_global_load_lds(
        (const __attribute__((address_space(1))) unsigned*)g,
        (__attribute__((address_space(3))) unsigned*)lds, 16, 0, 0);
}
__device__ __forceinline__ void async4(void* lds, const void* g) {
    __builtin_amdgcn_global_load_lds(
        (const __attribute__((address_space(1))) unsigned*)g,
        (__attribute__((address_space(3))) unsigned*)lds, 4, 0, 0);
}

// Kernel 0: sq[i] = ||f_i||^2 (always); Fbf = bf16(F) (if doFbf).
__global__ void prep_kernel(const float* __restrict__ F, ushort* __restrict__ Fbf,
                            float* __restrict__ sq, int doFbf) {
    int gtid = blockIdx.x * blockDim.x + threadIdx.x;
    int row  = gtid >> 6;
    int lane = threadIdx.x & 63;
    const float2 v = *(const float2*)(F + (size_t)row * DD + lane * 2);
    if (doFbf)
        ((ushort2*)(Fbf + (size_t)row * DD))[lane] = make_ushort2(f2bf(v.x), f2bf(v.y));
    float s = v.x * v.x + v.y * v.y;
    #pragma unroll
    for (int off = 32; off > 0; off >>= 1) s += __shfl_down(s, off);
    if (lane == 0) sq[row] = s;
}

// Kernel 1 (fast): per 128x128 S-tile, partial = sum S_ij*(sq_i+sq_j-2*f_i.f_j).
// R2 structure (measured 69.1us) with 512-thread blocks: 8 waves/block, each
// wave owns a 16-col j-window -> ~105 VGPR -> 16 waves/CU (2x R2) for better
// cross-wave phase stagger; per-block S amortization (64KB) unchanged.
__global__ __launch_bounds__(512, 4) void tile_kernel(
        const ushort* __restrict__ Fbf, const float* __restrict__ S,
        const float* __restrict__ sq, float* __restrict__ partials) {
    __shared__ ushort lI[BM * DD];   // F_i panel (B-operand), swizzled (32 KB)
    __shared__ ushort lJ[BM * DD];   // F_j panel (A-operand), swizzled (32 KB)
    __shared__ float  sqi[BM];
    __shared__ float  sqj[BM];
    __shared__ float  red[8];

    const int gi = blockIdx.y * BM, gj = blockIdx.x * BM;
    const int tid = threadIdx.x;
    const int w = tid >> 6, l = tid & 63;

    // ---- stage panels: linear LDS dest, pre-swizzled global src ----
    #pragma unroll
    for (int it = 0; it < 4; ++it) {
        const int chunk = it * 8 + w;            // 1 KB chunks, 32 per panel
        const int row = chunk * 4 + (l >> 4);    // LDS row this lane lands in
        const int src = ((l & 15) * 16) ^ ((row & 7) << 4);
        async16((char*)lI + chunk * 1024, (const char*)(Fbf + (size_t)(gi + row) * DD) + src);
        async16((char*)lJ + chunk * 1024, (const char*)(Fbf + (size_t)(gj + row) * DD) + src);
    }
    if (w < 4) {
        float* dstb = (w < 2 ? sqi : sqj) + (w & 1) * 64;
        const float* srcb = sq + (w < 2 ? gi : gj) + (w & 1) * 64 + l;
        async4(dstb, srcb);
    }
    __syncthreads();

    const int fr = l & 15;
    const int g  = l >> 4;
    const int jw = w * 16;            // wave's 16-col j window in tile

    // ---- S loads first (after barrier): fly under ds_reads + MFMAs ----
    f32x4 sv[8];
    const float* sb = S + (size_t)(gi + fr) * NN + gj + jw + g * 4;
    #pragma unroll
    for (int ct = 0; ct < 8; ++ct)
        sv[ct] = *(const f32x4*)(sb + (size_t)ct * 16 * NN);
    __builtin_amdgcn_sched_barrier(0);   // pin: S issued before MFMA/ds_read

    // ---- A fragments from F_j panel ----
    bf16x8 afrag[4];
    #pragma unroll
    for (int kk = 0; kk < 4; ++kk) {
        const int row = jw + fr;
        int byte = row * 256 + kk * 64 + g * 16;
        byte ^= (row & 7) << 4;
        afrag[kk] = *(const bf16x8*)((const char*)lJ + byte);
    }

    f32x4 acc[8];
    #pragma unroll
    for (int ct = 0; ct < 8; ++ct) acc[ct] = (f32x4){0.f, 0.f, 0.f, 0.f};

    // ---- MFMA: D = F_j . F_i^T (S loads in flight underneath) ----
    #pragma unroll
    for (int ct = 0; ct < 8; ++ct) {
        const int row = ct * 16 + fr;
        const int sw  = (row & 7) << 4;
        #pragma unroll
        for (int kk = 0; kk < 4; ++kk) {
            const bf16x8 bfrag = *(const bf16x8*)((const char*)lI + row * 256 +
                                                  ((kk * 64 + g * 16) ^ sw));
            acc[ct] = __builtin_amdgcn_mfma_f32_16x16x32_bf16(afrag[kk], bfrag, acc[ct], 0, 0, 0);
        }
    }

    // ---- consume: part += S * (sq_i + sq_j - 2*P) ----
    const float4 sjv = *(const float4*)(sqj + jw + g * 4);
    float part0 = 0.f, part1 = 0.f;
    #pragma unroll
    for (int ct = 0; ct < 8; ++ct) {
        const float sic = sqi[ct * 16 + fr];
        const f32x4 s4 = sv[ct];
        part0 += s4.x * ((sic + sjv.x) - 2.f * acc[ct][0]);
        part1 += s4.y * ((sic + sjv.y) - 2.f * acc[ct][1]);
        part0 += s4.z * ((sic + sjv.z) - 2.f * acc[ct][2]);
        part1 += s4.w * ((sic + sjv.w) - 2.f * acc[ct][3]);
    }
    float part = part0 + part1;

    // ---- deterministic block reduction ----
    #pragma unroll
    for (int off = 32; off > 0; off >>= 1) part += __shfl_down(part, off);
    if (l == 0) red[w] = part;
    __syncthreads();
    if (tid == 0)
        partials[blockIdx.y * gridDim.x + blockIdx.x] =
            ((red[0] + red[1]) + (red[2] + red[3])) +
            ((red[4] + red[5]) + (red[6] + red[7]));
}

// ---------------- fallback path (tiny workspace): R2-style ----------------
__global__ __launch_bounds__(256, 2) void tile_fb_kernel(
        const float* __restrict__ F, const float* __restrict__ S,
        const float* __restrict__ sq, float* __restrict__ partials) {
    __shared__ ushort lI[BM * DD];
    __shared__ ushort lJ[BM * DD];
    __shared__ float  sqi[BM];
    __shared__ float  sqj[BM];
    __shared__ float  red[4];

    const int gi = blockIdx.y * BM, gj = blockIdx.x * BM;
    const int tid = threadIdx.x;
    const int w = tid >> 6, l = tid & 63;

    const int r0 = tid >> 5;
    const int c4 = (tid & 31) * 4;
    #pragma unroll
    for (int it = 0; it < 16; ++it) {
        const int row = it * 8 + r0;
        const float4 va = *(const float4*)(F + (size_t)(gi + row) * DD + c4);
        const float4 vb = *(const float4*)(F + (size_t)(gj + row) * DD + c4);
        int byte = row * 256 + c4 * 2;
        byte ^= (row & 7) << 4;
        *(ushort4*)((char*)lI + byte) =
            make_ushort4(f2bf(va.x), f2bf(va.y), f2bf(va.z), f2bf(va.w));
        *(ushort4*)((char*)lJ + byte) =
            make_ushort4(f2bf(vb.x), f2bf(vb.y), f2bf(vb.z), f2bf(vb.w));
    }
    if (tid < 128) sqi[tid] = sq[gi + tid];
    else           sqj[tid - 128] = sq[gj + tid - 128];
    __syncthreads();

    const int fr = l & 15;
    const int g  = l >> 4;
    const int jw = w * 32;

    float4 sv0[8], sv1[8];
    #pragma unroll
    for (int ct = 0; ct < 8; ++ct) {
        const float* srow = S + (size_t)(gi + ct * 16 + fr) * NN + gj + jw + g * 4;
        sv0[ct] = *(const float4*)(srow);
        sv1[ct] = *(const float4*)(srow + 16);
    }

    bf16x8 afrag[2][4];
    #pragma unroll
    for (int kk = 0; kk < 4; ++kk) {
        int row = jw + fr;
        int byte = row * 256 + kk * 64 + g * 16; byte ^= (row & 7) << 4;
        afrag[0][kk] = *(const bf16x8*)((const char*)lJ + byte);
        row = jw + 16 + fr;
        byte = row * 256 + kk * 64 + g * 16; byte ^= (row & 7) << 4;
        afrag[1][kk] = *(const bf16x8*)((const char*)lJ + byte);
    }

    f32x4 acc[2][8];
    #pragma unroll
    for (int ct = 0; ct < 8; ++ct) {
        acc[0][ct] = (f32x4){0.f, 0.f, 0.f, 0.f};
        acc[1][ct] = (f32x4){0.f, 0.f, 0.f, 0.f};
    }
    #pragma unroll
    for (int ct = 0; ct < 8; ++ct) {
        #pragma unroll
        for (int kk = 0; kk < 4; ++kk) {
            const int row = ct * 16 + fr;
            int byte = row * 256 + kk * 64 + g * 16; byte ^= (row & 7) << 4;
            const bf16x8 bfrag = *(const bf16x8*)((const char*)lI + byte);
            acc[0][ct] = __builtin_amdgcn_mfma_f32_16x16x32_bf16(afrag[0][kk], bfrag, acc[0][ct], 0, 0, 0);
            acc[1][ct] = __builtin_amdgcn_mfma_f32_16x16x32_bf16(afrag[1][kk], bfrag, acc[1][ct], 0, 0, 0);
        }
    }

    const float4 sj0 = *(const float4*)(sqj + jw + g * 4);
    const float4 sj1 = *(const float4*)(sqj + jw + 16 + g * 4);
    float part = 0.f;
    #pragma unroll
    for (int ct = 0; ct < 8; ++ct) {
        const float sic = sqi[ct * 16 + fr];
        const float4 s0 = sv0[ct], s1 = sv1[ct];
        part += s0.x * (sic + sj0.x - 2.f * acc[0][ct][0]);
        part += s0.y * (sic + sj0.y - 2.f * acc[0][ct][1]);
        part += s0.z * (sic + sj0.z - 2.f * acc[0][ct][2]);
        part += s0.w * (sic + sj0.w - 2.f * acc[0][ct][3]);
        part += s1.x * (sic + sj1.x - 2.f * acc[1][ct][0]);
        part += s1.y * (sic + sj1.y - 2.f * acc[1][ct][1]);
        part += s1.z * (sic + sj1.z - 2.f * acc[1][ct][2]);
        part += s1.w * (sic + sj1.w - 2.f * acc[1][ct][3]);
    }

    #pragma unroll
    for (int off = 32; off > 0; off >>= 1) part += __shfl_down(part, off);
    if (l == 0) red[w] = part;
    __syncthreads();
    if (tid == 0)
        partials[blockIdx.y * gridDim.x + blockIdx.x] = (red[0] + red[1]) + (red[2] + red[3]);
}

__global__ void reduce_kernel(const float* __restrict__ partials, float* __restrict__ out) {
    __shared__ float sm[256];
    const int t = threadIdx.x;
    float s = 0.f;
    for (int i = t; i < NTILE * NTILE; i += 256) s += partials[i];
    sm[t] = s;
    __syncthreads();
    for (int off = 128; off > 0; off >>= 1) {
        if (t < off) sm[t] += sm[t + off];
        __syncthreads();
    }
    if (t == 0) out[0] = sm[0];
}

extern "C" void kernel_launch(void* const* d_in, const int* in_sizes, int n_in,
                              void* d_out, int out_size, void* d_ws, size_t ws_size,
                              hipStream_t stream) {
    const float* F = (const float*)d_in[0];
    const float* S = (const float*)d_in[1];
    float* sq       = (float*)d_ws;                       // 32 KB
    float* partials = sq + NN;                            // 16 KB
    ushort* Fbf     = (ushort*)((char*)d_ws + 48 * 1024); // 2 MB
    float* out      = (float*)d_out;

    const size_t need = 48 * 1024 + (size_t)NN * DD * 2 + 256;
    const int fast = (ws_size >= need) ? 1 : 0;

    prep_kernel<<<NN / 4, 256, 0, stream>>>(F, Fbf, sq, fast);
    dim3 grid(NTILE, NTILE);
    if (fast)
        tile_kernel<<<grid, 512, 0, stream>>>(Fbf, S, sq, partials);
    else
        tile_fb_kernel<<<grid, 256, 0, stream>>>(F, S, sq, partials);
    reduce_kernel<<<1, 256, 0, stream>>>(partials, out);
}